// Round 8
// baseline (652.042 us; speedup 1.0000x reference)
//
#include <hip/hip_runtime.h>
#include <hip/hip_bf16.h>

// B=4, N=256, F=64, H=256, A=16, T=3. BN=1024.
// 12 launches: conv, preB(pre1+pre2 || wcomb-GEMM), 3x(hcat[+gru prologue],
// msg, gi), readout[+gru]. bf16 MFMA 16x16x32, BK=64 VGPR-pipelined, padded
// LDS. Split hi/lo activations + dup-K weights (~fp32). gi = Ehat@Wcomb +
// bih + deg*v2 where Wcomb = msgW2@Wih (MFMA, exact), v2 = msgb2@Wih.

typedef unsigned short ushort_t;
typedef short bf8_t __attribute__((ext_vector_type(8)));
typedef float f4_t  __attribute__((ext_vector_type(4)));

#define LDA 72

// ---- ushort offsets ----
#define UB_NFB     0          // [1024][64]
#define UB_PW1T    65536      // [256][64]
#define UB_PW2T    81920      // [256][512] dup
#define UB_WCATT   212992     // [1280][512] dup
#define UB_WIHT    868352     // [768][256]
#define UB_MSGW2S  1064960    // [256][256] msgW2 staged bf16
#define UB_WCOMBT  1130496    // [768][896]: per n: [Whi(256)|0|Whi|0|Wlo|0]
#define UB_X2      1818624    // [1024][512] hi|lo
#define UB_H2      2342912    // [1024][512] hi|lo
#define UB_EHAT    2867200    // [1024][896]: [Ehi(256)|0|Elo|0|Ehi|0]
// ---- float offsets ----
#define F_PREB1    1892352    // 256
#define F_PREB2    1892608    // 256
#define F_BCAT     1892864    // 1280
#define F_BIH      1894144    // 768
#define F_ROW1     1894912    // 65536
#define F_ROB1     1960448    // 256
#define F_ROW2     1960704    // 4096
#define F_ROB2     1964800    // 16
#define F_V2       1964816    // 768
#define F_DEG      1965584    // 1024
#define F_HA       1966608    // 262144
#define F_HB       2228752    // 262144
#define F_HCATA    2490896    // 1310720
#define F_HCATB    3801616    // 1310720
#define F_GI       5112336    // 786432
#define F_FLAG     5898768    // 1 int  (~23.6 MB)

// ---- conv index space ----
#define CV1 65536      // NFB
#define CV2 81920      // PW1T
#define CV3 212992     // PW2T
#define CV4 868352     // WCATT
#define CV5 1064960    // WIHT
#define CV6 1130496    // MSGW2S
#define CV7 1204224    // wcombt zero slots (768*96)
#define CV_TOTAL 1276688  // + 72464 fp32 tail

__device__ __forceinline__ float bf2f(ushort_t u) {
    return __uint_as_float(((unsigned int)u) << 16);
}
__device__ __forceinline__ ushort_t f2b(float v) {
    __hip_bfloat16 b = __float2bfloat16(v);
    return *reinterpret_cast<ushort_t*>(&b);
}
__device__ __forceinline__ float relu(float v) { return v < 0.f ? 0.f : v; }
__device__ __forceinline__ float ld(const void* p, int i, int isf32) {
    return isf32 ? ((const float*)p)[i] : bf2f(((const ushort_t*)p)[i]);
}

// Shared MFMA core: acc += A[bm:+128, :K] @ Bt[bn:+128, :K]^T (BK=64, prefetch)
__device__ __forceinline__ void mgemm_core(
    const ushort_t* __restrict__ A, const ushort_t* __restrict__ Bt,
    int K, int bm, int bn, ushort_t* As, ushort_t* Bs, f4_t acc[4][4])
{
    const int t = threadIdx.x;
    const int wave = t >> 6, lane = t & 63;
    const int ln = lane & 15, quad = lane >> 4;
    const int wm = (wave >> 1) * 64, wn = (wave & 1) * 64;
    const int sr = t >> 3, sc = (t & 7) << 3;

    bf8_t ga[4], gb[4];
#pragma unroll
    for (int r = 0; r < 4; ++r) {
        ga[r] = *(const bf8_t*)(&A[(bm + sr + r * 32) * K + sc]);
        gb[r] = *(const bf8_t*)(&Bt[(bn + sr + r * 32) * K + sc]);
    }
    for (int k0 = 0;;) {
        __syncthreads();
#pragma unroll
        for (int r = 0; r < 4; ++r) {
            *(bf8_t*)(&As[(sr + r * 32) * LDA + sc]) = ga[r];
            *(bf8_t*)(&Bs[(sr + r * 32) * LDA + sc]) = gb[r];
        }
        __syncthreads();
        const int kn = k0 + 64;
        if (kn < K) {
#pragma unroll
            for (int r = 0; r < 4; ++r) {
                ga[r] = *(const bf8_t*)(&A[(bm + sr + r * 32) * K + kn + sc]);
                gb[r] = *(const bf8_t*)(&Bt[(bn + sr + r * 32) * K + kn + sc]);
            }
        }
#pragma unroll
        for (int half = 0; half < 2; ++half) {
            bf8_t af[4], bfr[4];
#pragma unroll
            for (int i = 0; i < 4; ++i) {
                af[i]  = *(const bf8_t*)(&As[(wm + i * 16 + ln) * LDA + half * 32 + quad * 8]);
                bfr[i] = *(const bf8_t*)(&Bs[(wn + i * 16 + ln) * LDA + half * 32 + quad * 8]);
            }
#pragma unroll
            for (int mi = 0; mi < 4; ++mi)
#pragma unroll
                for (int ni = 0; ni < 4; ++ni)
                    acc[mi][ni] = __builtin_amdgcn_mfma_f32_16x16x32_bf16(
                        af[mi], bfr[ni], acc[mi][ni], 0, 0, 0);
        }
        k0 = kn;
        if (k0 >= K) break;
    }
}

// ---- conv: stage all weights (no serial Wcomb!), detect dtype, compute v2 ----
__global__ __launch_bounds__(256) void conv_kernel(
    const void* nf,
    const void* preW1, const void* preb1, const void* preW2, const void* preb2,
    const void* msgW1, const void* msgb1, const void* msgW2, const void* msgb2,
    const void* gruWih, const void* gruWhh, const void* grubih, const void* grubhh,
    const void* roW1, const void* rob1, const void* roW2, const void* rob2,
    float* __restrict__ w)
{
    const int bid = blockIdx.x, t = threadIdx.x;
    ushort_t* wb = (ushort_t*)w;

    __shared__ int cnt;
    if (t == 0) cnt = 0;
    __syncthreads();
    {
        const ushort_t* nf16 = (const ushort_t*)nf;
        int bad = 0;
        for (int i = 0; i < 8; ++i) {
            ushort_t u = nf16[(t * 8 + i) * 2];
            int ex = (u >> 7) & 0xFF;
            if ((u & 0x7fff) != 0 && (ex < 100 || ex > 140)) bad++;
        }
        atomicAdd(&cnt, bad);
    }
    __syncthreads();
    const int f32 = (cnt > 512) ? 1 : 0;
    if (bid == 0 && t == 0) ((int*)(w + F_FLAG))[0] = f32;

    for (int e = bid * 256 + t; e < CV_TOTAL; e += 256 * 256) {
        if (e < CV1) {
            wb[UB_NFB + e] = f2b(ld(nf, e, f32));
        } else if (e < CV2) {                       // preW1^T [256][64]
            int i = e - CV1; int n = i >> 6, k = i & 63;
            wb[UB_PW1T + i] = f2b(ld(preW1, k * 256 + n, f32));
        } else if (e < CV3) {                       // preW2^T dup [256][512]
            int i = e - CV2; int n = i >> 9, k = i & 255;
            wb[UB_PW2T + i] = f2b(ld(preW2, k * 256 + n, f32));
        } else if (e < CV4) {                       // Wcat^T dup [1280][512]
            int i = e - CV3; int n = i >> 9, k = i & 255;
            float v;
            if (n < 256)      v = ld(msgW1, k * 256 + n, f32);
            else if (n < 512) v = ld(msgW1, (256 + k) * 256 + (n - 256), f32);
            else              v = ld(gruWhh, k * 768 + (n - 512), f32);
            wb[UB_WCATT + i] = f2b(v);
        } else if (e < CV5) {                       // Wih^T [768][256]
            int i = e - CV4; int n = i >> 8, k = i & 255;
            wb[UB_WIHT + i] = f2b(ld(gruWih, k * 768 + n, f32));
        } else if (e < CV6) {                       // msgW2 staged [256][256]
            int i = e - CV5;
            wb[UB_MSGW2S + i] = f2b(ld(msgW2, i, f32));
        } else if (e < CV7) {                       // wcombt dead slots -> 0
            int i = e - CV6; int n = i / 96, s = i - n * 96;
            int slot = (s < 32) ? (256 + s) : (s < 64) ? (544 + s - 32) : (832 + s - 64);
            wb[UB_WCOMBT + n * 896 + slot] = 0;
        } else {                                    // fp32 tail
            int f = e - CV7;
            float v;
            if (f < 256)        v = ld(preb1, f, f32);
            else if (f < 512)   v = ld(preb2, f - 256, f32);
            else if (f < 1792) {
                int c = f - 512;
                if (c < 256)      v = ld(msgb1, c, f32);
                else if (c < 512) v = 0.f;
                else              v = ld(grubhh, c - 512, f32);
            }
            else if (f < 2560)  v = ld(grubih, f - 1792, f32);
            else if (f < 68096) v = ld(roW1, f - 2560, f32);
            else if (f < 68352) v = ld(rob1, f - 68096, f32);
            else if (f < 72448) v = ld(roW2, f - 68352, f32);
            else                v = ld(rob2, f - 72448, f32);
            w[F_PREB1 + f] = v;
        }
    }

    // v2[n] = msgb2 . Wih[:,n]  (block 0, runs parallel to other blocks)
    if (bid == 0) {
        __shared__ float b2s[256];
        b2s[t] = ld(msgb2, t, f32);
        __syncthreads();
        for (int n = t; n < 768; n += 256) {
            float a = 0.f;
#pragma unroll 8
            for (int c = 0; c < 256; ++c) a += b2s[c] * ld(gruWih, c * 768 + n, f32);
            w[F_V2 + n] = a;
        }
    }
}

// ---- preB: blocks 0..7 = pre1+pre2 (row-local chain); 8..19 = Wcomb GEMM ----
__global__ __launch_bounds__(256) void preB_kernel(float* __restrict__ w)
{
    __shared__ ushort_t As[128 * LDA];
    __shared__ ushort_t Bs[128 * LDA];
    ushort_t* wb = (ushort_t*)w;
    const int bid = blockIdx.x, t = threadIdx.x;
    const int wave = t >> 6, lane = t & 63;
    const int ln = lane & 15, quad = lane >> 4;
    const int wm = (wave >> 1) * 64, wn = (wave & 1) * 64;

    if (bid < 8) {
        const int bm = bid * 128;
        // pre1: X = relu(NF@preW1+b1) -> X2 hi|lo (own rows)
        for (int bnI = 0; bnI < 2; ++bnI) {
            f4_t acc[4][4] = {};
            mgemm_core(wb + UB_NFB, wb + UB_PW1T, 64, bm, bnI * 128, As, Bs, acc);
#pragma unroll
            for (int mi = 0; mi < 4; ++mi)
#pragma unroll
                for (int ni = 0; ni < 4; ++ni) {
                    int col = bnI * 128 + wn + ni * 16 + ln;
                    float bb = w[F_PREB1 + col];
#pragma unroll
                    for (int r = 0; r < 4; ++r) {
                        int row = bm + wm + mi * 16 + quad * 4 + r;
                        float v = relu(acc[mi][ni][r] + bb);
                        ushort_t hi = f2b(v);
                        wb[UB_X2 + row * 512 + col] = hi;
                        wb[UB_X2 + row * 512 + 256 + col] = f2b(v - bf2f(hi));
                    }
                }
        }
        __syncthreads();   // X2 writes drained before read-back
        // pre2: h = X2@preW2dup + b2 -> F_HA + H2 hi|lo
        for (int bnI = 0; bnI < 2; ++bnI) {
            f4_t acc[4][4] = {};
            mgemm_core(wb + UB_X2, wb + UB_PW2T, 512, bm, bnI * 128, As, Bs, acc);
#pragma unroll
            for (int mi = 0; mi < 4; ++mi)
#pragma unroll
                for (int ni = 0; ni < 4; ++ni) {
                    int col = bnI * 128 + wn + ni * 16 + ln;
                    float bb = w[F_PREB2 + col];
#pragma unroll
                    for (int r = 0; r < 4; ++r) {
                        int row = bm + wm + mi * 16 + quad * 4 + r;
                        float v = acc[mi][ni][r] + bb;
                        w[F_HA + row * 256 + col] = v;
                        ushort_t hi = f2b(v);
                        wb[UB_H2 + row * 512 + col] = hi;
                        wb[UB_H2 + row * 512 + 256 + col] = f2b(v - bf2f(hi));
                    }
                }
            __syncthreads();
        }
    } else {
        // Wcomb = msgW2 @ Wih (both exact bf16): 12 tiles of [256 k][768 n]
        const int tile = bid - 8;
        const int bm = (tile / 6) * 128, bn = (tile % 6) * 128;
        f4_t acc[4][4] = {};
        mgemm_core(wb + UB_MSGW2S, wb + UB_WIHT, 256, bm, bn, As, Bs, acc);
#pragma unroll
        for (int mi = 0; mi < 4; ++mi)
#pragma unroll
            for (int ni = 0; ni < 4; ++ni) {
                int n = bn + wn + ni * 16 + ln;
#pragma unroll
                for (int r = 0; r < 4; ++r) {
                    int k = bm + wm + mi * 16 + quad * 4 + r;
                    float v = acc[mi][ni][r];
                    ushort_t hi = f2b(v);
                    ushort_t lo = f2b(v - bf2f(hi));
                    wb[UB_WCOMBT + n * 896 + k] = hi;         // Whi
                    wb[UB_WCOMBT + n * 896 + 288 + k] = hi;   // Whi dup
                    wb[UB_WCOMBT + n * 896 + 576 + k] = lo;   // Wlo
                }
            }
    }
}

// ---- hcat: optional GRU prologue (redundant per column-tile) + GEMM ----
__global__ __launch_bounds__(256) void hcat_kernel(
    ushort_t* __restrict__ H2, const ushort_t* __restrict__ Wcatt,
    const float* __restrict__ bcat, float* __restrict__ hcatNew,
    const float* __restrict__ giOld, const float* __restrict__ hcatOld,
    const float* __restrict__ hOld, float* __restrict__ hNew)
{
    __shared__ ushort_t As[128 * LDA];
    __shared__ ushort_t Bs[128 * LDA];
    const int t = threadIdx.x;
    const int bm = blockIdx.y * 128, bn = blockIdx.x * 128;

    if (giOld) {
#pragma unroll 2
        for (int i = 0; i < 128; ++i) {
            const int row = bm + i;
            const float* gir = giOld + row * 768;
            const float* ghr = hcatOld + row * 1280 + 512;
            float ir = gir[t], iz = gir[256 + t], in = gir[512 + t];
            float hr = ghr[t], hz = ghr[256 + t], hn = ghr[512 + t];
            float r = 1.f / (1.f + __expf(-(ir + hr)));
            float z = 1.f / (1.f + __expf(-(iz + hz)));
            float n = tanhf(in + r * hn);
            float hv = (1.f - z) * n + z * hOld[row * 256 + t];
            hNew[row * 256 + t] = hv;
            ushort_t hb = f2b(hv);
            H2[row * 512 + t] = hb;
            H2[row * 512 + 256 + t] = f2b(hv - bf2f(hb));
        }
        __syncthreads();
    }

    f4_t acc[4][4] = {};
    mgemm_core(H2, Wcatt, 512, bm, bn, As, Bs, acc);
    const int wave = t >> 6, lane = t & 63;
    const int ln = lane & 15, quad = lane >> 4;
    const int wm = (wave >> 1) * 64, wn = (wave & 1) * 64;
#pragma unroll
    for (int mi = 0; mi < 4; ++mi)
#pragma unroll
        for (int ni = 0; ni < 4; ++ni) {
            int col = bn + wn + ni * 16 + ln;
            float bb = bcat[col];
#pragma unroll
            for (int r = 0; r < 4; ++r) {
                int row = bm + wm + mi * 16 + quad * 4 + r;
                hcatNew[row * 1280 + col] = acc[mi][ni][r] + bb;
            }
        }
}

// ---- msg: 4 rows/block; Ehat=[Ehi|0|Elo|0|Ehi|0]; deg -> F_DEG ----
__global__ __launch_bounds__(256) void msg_kernel(
    const float* __restrict__ hcat, const int* __restrict__ adj,
    ushort_t* __restrict__ ehat, float* __restrict__ deg)
{
    __shared__ float adjf[4 * 256];
    const int t = threadIdx.x;
    const int r0 = blockIdx.x * 4;
#pragma unroll
    for (int rr = 0; rr < 4; ++rr)
        adjf[rr * 256 + t] = (float)adj[(r0 + rr) * 256 + t];
    float hi_[4];
#pragma unroll
    for (int rr = 0; rr < 4; ++rr)
        hi_[rr] = hcat[(r0 + rr) * 1280 + t];
    const float* hjb = hcat + (r0 >> 8) * 256 * 1280 + 256;
    __syncthreads();
    float acc[4] = {}, cnt_[4] = {};
#pragma unroll 4
    for (int j = 0; j < 256; ++j) {
        float hjv = hjb[j * 1280 + t];
#pragma unroll
        for (int rr = 0; rr < 4; ++rr) {
            float a = adjf[rr * 256 + j];
            acc[rr] += a * relu(hi_[rr] + hjv);
            cnt_[rr] += a;
        }
    }
#pragma unroll
    for (int rr = 0; rr < 4; ++rr) {
        const int row = r0 + rr;
        ushort_t h16 = f2b(acc[rr]);
        ushort_t l16 = f2b(acc[rr] - bf2f(h16));
        ehat[row * 896 + t] = h16;
        ehat[row * 896 + 288 + t] = l16;
        ehat[row * 896 + 576 + t] = h16;
        if (t < 32) {
            ehat[row * 896 + 256 + t] = 0;
            ehat[row * 896 + 544 + t] = 0;
            ehat[row * 896 + 832 + t] = 0;
            ehat[row * 896 + 864 + t] = 0;
        }
        if (t == 0) deg[row] = cnt_[rr];
    }
}

// ---- gi GEMM: C = Ehat@Wcomb + bih + deg*v2 ----
__global__ __launch_bounds__(256) void gi_kernel(
    const ushort_t* __restrict__ A, const ushort_t* __restrict__ Bt,
    const float* __restrict__ bias, float* __restrict__ C,
    const float* __restrict__ degp, const float* __restrict__ v2p)
{
    __shared__ ushort_t As[128 * LDA];
    __shared__ ushort_t Bs[128 * LDA];
    const int t = threadIdx.x;
    const int bm = blockIdx.y * 128, bn = blockIdx.x * 128;
    f4_t acc[4][4] = {};
    mgemm_core(A, Bt, 896, bm, bn, As, Bs, acc);
    const int wave = t >> 6, lane = t & 63;
    const int ln = lane & 15, quad = lane >> 4;
    const int wm = (wave >> 1) * 64, wn = (wave & 1) * 64;
#pragma unroll
    for (int mi = 0; mi < 4; ++mi) {
#pragma unroll
        for (int r = 0; r < 4; ++r) {
            int row = bm + wm + mi * 16 + quad * 4 + r;
            float dg = degp[row];
#pragma unroll
            for (int ni = 0; ni < 4; ++ni) {
                int col = bn + wn + ni * 16 + ln;
                C[row * 768 + col] = acc[mi][ni][r] + bias[col] + dg * v2p[col];
            }
        }
    }
}

// ---- readout: fused final GRU + sum + MLP ----
__global__ __launch_bounds__(256) void readout_kernel(
    const float* __restrict__ w_all, const float* __restrict__ hOld,
    const float* __restrict__ gi, const float* __restrict__ hcatOld,
    void* __restrict__ out)
{
    const int b = blockIdx.x, t = threadIdx.x;
    float g = 0.f;
#pragma unroll 2
    for (int i = 0; i < 256; ++i) {
        const int row = b * 256 + i;
        const float* gir = gi + row * 768;
        const float* ghr = hcatOld + row * 1280 + 512;
        float ir = gir[t], iz = gir[256 + t], in = gir[512 + t];
        float hr = ghr[t], hz = ghr[256 + t], hn = ghr[512 + t];
        float r = 1.f / (1.f + __expf(-(ir + hr)));
        float z = 1.f / (1.f + __expf(-(iz + hz)));
        float n = tanhf(in + r * hn);
        g += (1.f - z) * n + z * hOld[row * 256 + t];
    }
    __shared__ float gl[256], t1[256];
    gl[t] = g;
    __syncthreads();
    float acc = w_all[F_ROB1 + t];
    for (int k = 0; k < 256; ++k) acc += gl[k] * w_all[F_ROW1 + k * 256 + t];
    t1[t] = relu(acc);
    __syncthreads();
    if (t < 16) {
        float q = w_all[F_ROB2 + t];
        for (int k = 0; k < 256; ++k) q += t1[k] * w_all[F_ROW2 + k * 16 + t];
        if (((const int*)(w_all + F_FLAG))[0]) ((float*)out)[b * 16 + t] = q;
        else ((__hip_bfloat16*)out)[b * 16 + t] = __float2bfloat16(q);
    }
}

extern "C" void kernel_launch(void* const* d_in, const int* in_sizes, int n_in,
                              void* d_out, int out_size, void* d_ws, size_t ws_size,
                              hipStream_t stream) {
    float* w = (float*)d_ws;
    ushort_t* wb = (ushort_t*)d_ws;

    static const int dictSz[18]  = {65536,262144,16384,256,65536,256,131072,256,65536,256,
                                    196608,196608,768,768,65536,256,4096,16};
    static const int alphaSz[18] = {262144,196608,196608,768,768,131072,65536,256,256,
                                    65536,16384,65536,256,256,65536,4096,256,16};
    static const int alphaPos[18] = {9,0,10,12,11,13,5,7,6,8,2,1,4,3,14,16,15,17};
    bool dictOK = true, alphaOK = true;
    for (int i = 0; i < 18 && i < n_in; ++i) {
        if (in_sizes[i] != dictSz[i])  dictOK = false;
        if (in_sizes[i] != alphaSz[i]) alphaOK = false;
    }
    const void* P[18];
    for (int l = 0; l < 18; ++l) P[l] = d_in[(!dictOK && alphaOK) ? alphaPos[l] : l];
    const int* adj = (const int*)P[1];

    conv_kernel<<<256, 256, 0, stream>>>(
        P[0], P[2], P[3], P[4], P[5], P[6], P[7], P[8], P[9],
        P[10], P[11], P[12], P[13], P[14], P[15], P[16], P[17], w);
    preB_kernel<<<20, 256, 0, stream>>>(w);

    float* HCAT[2] = {w + F_HCATA, w + F_HCATB};
    float* HBUF[2] = {w + F_HA, w + F_HB};

    // it0 (no GRU prologue; h from pre)
    hcat_kernel<<<dim3(10, 8), 256, 0, stream>>>(
        wb + UB_H2, wb + UB_WCATT, w + F_BCAT, HCAT[0],
        (const float*)0, (const float*)0, (const float*)0, (float*)0);
    msg_kernel<<<256, 256, 0, stream>>>(HCAT[0], adj, wb + UB_EHAT, w + F_DEG);
    gi_kernel<<<dim3(6, 8), 256, 0, stream>>>(
        wb + UB_EHAT, wb + UB_WCOMBT, w + F_BIH, w + F_GI, w + F_DEG, w + F_V2);

    // it1, it2 (GRU fused as hcat prologue; buffers ping-pong)
    for (int it = 1; it < 3; ++it) {
        hcat_kernel<<<dim3(10, 8), 256, 0, stream>>>(
            wb + UB_H2, wb + UB_WCATT, w + F_BCAT, HCAT[it & 1],
            w + F_GI, HCAT[(it - 1) & 1], HBUF[(it - 1) & 1], HBUF[it & 1]);
        msg_kernel<<<256, 256, 0, stream>>>(HCAT[it & 1], adj, wb + UB_EHAT, w + F_DEG);
        gi_kernel<<<dim3(6, 8), 256, 0, stream>>>(
            wb + UB_EHAT, wb + UB_WCOMBT, w + F_BIH, w + F_GI, w + F_DEG, w + F_V2);
    }

    // readout: final GRU fused (h_old = HBUF[0] after it2, gh = HCAT[0])
    readout_kernel<<<4, 256, 0, stream>>>(w, HBUF[0], w + F_GI, HCAT[0], d_out);
}